// Round 1
// baseline (433.685 us; speedup 1.0000x reference)
//
#include <hip/hip_runtime.h>
#include <hip/hip_bf16.h>

// MHCLayerAITER: x[B,4,2048] fp32 -> out[B,4,2048] fp32
// out[b,i,c] = sum_j M[i,j]*x[b,j,c] + 2*sig(H_post[i]) * y_norm[b,c]
// y_norm[b,c] = bf16(sum_j sig(H_pre[j])*x[b,j,c]) / rms_b * bf16(w[c])
// M = sinkhorn3(exp(H_res))  (4x4, tiny -> precomputed once into d_ws)
//
// R1 theory: prior version (424 us) = ~1.27 TB/s, only ~20% of HBM roofline
// (ideal 512 MiB -> ~90 us). Per-block serial chain (cold load latency ->
// barrier drain -> store -> exit) limited issue rate. This version: each
// block handles BPB=4 consecutive b's with a register double buffer, so
// the next batch's nt loads are in flight while the current batch computes
// and stores (vmcnt is in-order: waiting on older loads leaves newer
// prefetch loads outstanding). Buffer selection is manually unrolled with
// static array names -> registers, never scratch.

namespace {

constexpr int N = 4;
constexpr int C = 2048;
constexpr int BLOCK = 256;
constexpr int CPT = C / BLOCK;   // 8 c-values per thread
constexpr int VEC = CPT / 4;     // 2 float4 chunks per n-row
constexpr int BPB = 4;           // batches (b values) per block
constexpr float EPSF = 1e-6f;

typedef float f4 __attribute__((ext_vector_type(4)));

__device__ __forceinline__ float bf16r(float v) {
    return __bfloat162float(__float2bfloat16(v));
}

// ---- tiny setup: sigmoids + sinkhorn(exp(H_res)) -> cst[24] in d_ws ----
// cst[0..3]  = sigmoid(H_pre)
// cst[4..7]  = 2*sigmoid(H_post)
// cst[8..23] = M row-major
__global__ void setup_kernel(const float* __restrict__ H_pre,
                             const float* __restrict__ H_post,
                             const float* __restrict__ H_res,
                             float* __restrict__ cst) {
    if (threadIdx.x != 0 || blockIdx.x != 0) return;
    float P[N][N];
    #pragma unroll
    for (int j = 0; j < N; ++j) {
        cst[j]     = 1.0f / (1.0f + expf(-H_pre[j]));
        cst[N + j] = 2.0f / (1.0f + expf(-H_post[j]));
    }
    #pragma unroll
    for (int i = 0; i < N; ++i)
        #pragma unroll
        for (int j = 0; j < N; ++j)
            P[i][j] = expf(H_res[i * N + j]);
    #pragma unroll
    for (int it = 0; it < 3; ++it) {
        #pragma unroll
        for (int i = 0; i < N; ++i) {
            float rs = P[i][0] + P[i][1] + P[i][2] + P[i][3] + EPSF;
            #pragma unroll
            for (int j = 0; j < N; ++j) P[i][j] /= rs;
        }
        #pragma unroll
        for (int j = 0; j < N; ++j) {
            float cs = P[0][j] + P[1][j] + P[2][j] + P[3][j] + EPSF;
            #pragma unroll
            for (int i = 0; i < N; ++i) P[i][j] /= cs;
        }
    }
    #pragma unroll
    for (int i = 0; i < N; ++i)
        #pragma unroll
        for (int j = 0; j < N; ++j)
            cst[2 * N + i * N + j] = P[i][j];
}

// issue the 8 nt float4 loads for one b-row into a register buffer
__device__ __forceinline__ void load_x(const float* __restrict__ x,
                                       size_t base, int t,
                                       float (&xs)[N][CPT]) {
    #pragma unroll
    for (int j = 0; j < N; ++j) {
        #pragma unroll
        for (int v = 0; v < VEC; ++v) {
            const f4 tmp = __builtin_nontemporal_load(
                (const f4*)(x + base + (size_t)j * C + (size_t)(v * BLOCK + t) * 4));
            #pragma unroll
            for (int k = 0; k < 4; ++k) xs[j][v * 4 + k] = tmp[k];
        }
    }
}

// aggregate -> bf16 round -> rms reduce -> mix + combine -> nt store
__device__ __forceinline__ void process_b(const float (&xs)[N][CPT],
                                          const float (&ws)[CPT],
                                          const float (&pre)[N],
                                          const float (&post)[N],
                                          const float (&M)[N][N],
                                          float (&sr)[BLOCK / 64],
                                          int t, size_t base,
                                          float* __restrict__ out) {
    // sigmoid-weighted aggregate, bf16 round, sum of squares
    float agg[CPT];
    float ss = 0.0f;
    #pragma unroll
    for (int k = 0; k < CPT; ++k) {
        float a = pre[0] * xs[0][k] + pre[1] * xs[1][k]
                + pre[2] * xs[2][k] + pre[3] * xs[3][k];
        a = bf16r(a);
        agg[k] = a;
        ss += a * a;
    }

    // single-barrier block reduction over C for rms
    #pragma unroll
    for (int off = 32; off > 0; off >>= 1) ss += __shfl_xor(ss, off, 64);
    if ((t & 63) == 0) sr[t >> 6] = ss;
    __syncthreads();
    float tot = 0.0f;
    #pragma unroll
    for (int i = 0; i < BLOCK / 64; ++i) tot += sr[i];
    const float rinv = 1.0f / sqrtf(tot * (1.0f / (float)C) + EPSF);

    // y_norm hoisted out of the 4-row output loop
    float yn[CPT];
    #pragma unroll
    for (int k = 0; k < CPT; ++k) yn[k] = agg[k] * rinv * ws[k];

    // mix streams + combine, write all 4 output rows (nt stores)
    #pragma unroll
    for (int i = 0; i < N; ++i) {
        #pragma unroll
        for (int v = 0; v < VEC; ++v) {
            f4 o;
            #pragma unroll
            for (int k = 0; k < 4; ++k) {
                const int idx = v * 4 + k;
                o[k] = M[i][0] * xs[0][idx] + M[i][1] * xs[1][idx]
                     + M[i][2] * xs[2][idx] + M[i][3] * xs[3][idx]
                     + post[i] * yn[idx];
            }
            __builtin_nontemporal_store(
                o, (f4*)(out + base + (size_t)i * C + (size_t)(v * BLOCK + t) * 4));
        }
    }
}

__global__ __launch_bounds__(BLOCK) void mhc_kernel(
    const float* __restrict__ x,     // [B,N,C]
    const float* __restrict__ w,     // [C]
    const float* __restrict__ cst,   // [24] precomputed constants
    float* __restrict__ out,         // [B,N,C]
    int B)
{
    const int t = threadIdx.x;
    const int b0 = blockIdx.x * BPB;
    if (b0 >= B) return;
    const int nb = (B - b0 < BPB) ? (B - b0) : BPB;  // block-uniform

    __shared__ float s_red[2][BLOCK / 64];   // parity-alternated: 1 barrier/batch

    // wave-uniform constant loads -> SGPRs (amortized over BPB batches)
    float pre[N], post[N], M[N][N];
    #pragma unroll
    for (int j = 0; j < N; ++j) {
        pre[j]  = cst[j];
        post[j] = cst[N + j];
    }
    #pragma unroll
    for (int i = 0; i < N; ++i)
        #pragma unroll
        for (int j = 0; j < N; ++j)
            M[i][j] = cst[2 * N + i * N + j];

    // weight is reused by all blocks -> cached loads
    float ws[CPT];
    #pragma unroll
    for (int v = 0; v < VEC; ++v) {
        const f4 tmp = *(const f4*)(w + (size_t)(v * BLOCK + t) * 4);
        #pragma unroll
        for (int k = 0; k < 4; ++k) ws[v * 4 + k] = bf16r(tmp[k]);
    }

    const size_t row = (size_t)N * C;
    float xsA[N][CPT], xsB[N][CPT];

    // ---- manually unrolled 1-deep software pipeline (static buffer names,
    //      so both buffers live in registers; vmcnt in-order => waiting on
    //      the current buffer leaves the prefetch loads outstanding) ----
    load_x(x, (size_t)b0 * row, t, xsA);                       // batch 0

    if (nb > 1) load_x(x, (size_t)(b0 + 1) * row, t, xsB);     // prefetch 1
    process_b(xsA, ws, pre, post, M, s_red[0], t, (size_t)b0 * row, out);

    if (nb > 1) {
        if (nb > 2) load_x(x, (size_t)(b0 + 2) * row, t, xsA); // prefetch 2
        process_b(xsB, ws, pre, post, M, s_red[1], t, (size_t)(b0 + 1) * row, out);
    }
    if (nb > 2) {
        if (nb > 3) load_x(x, (size_t)(b0 + 3) * row, t, xsB); // prefetch 3
        process_b(xsA, ws, pre, post, M, s_red[0], t, (size_t)(b0 + 2) * row, out);
    }
    if (nb > 3) {
        process_b(xsB, ws, pre, post, M, s_red[1], t, (size_t)(b0 + 3) * row, out);
    }
}

}  // namespace

extern "C" void kernel_launch(void* const* d_in, const int* in_sizes, int n_in,
                              void* d_out, int out_size, void* d_ws, size_t ws_size,
                              hipStream_t stream) {
    const float* x      = (const float*)d_in[0];
    const float* w      = (const float*)d_in[1];
    const float* H_pre  = (const float*)d_in[2];
    const float* H_post = (const float*)d_in[3];
    const float* H_res  = (const float*)d_in[4];
    float* out = (float*)d_out;
    float* cst = (float*)d_ws;   // 24 floats

    const int B = in_sizes[0] / (N * C);   // 8192

    setup_kernel<<<dim3(1), dim3(1), 0, stream>>>(H_pre, H_post, H_res, cst);

    const int grid = (B + BPB - 1) / BPB;  // 2048 blocks x 4 waves
    mhc_kernel<<<dim3(grid), dim3(BLOCK), 0, stream>>>(x, w, cst, out, B);
}

// Round 3
// 432.554 us; speedup vs baseline: 1.0026x; 1.0026x over previous
//
#include <hip/hip_runtime.h>
#include <hip/hip_bf16.h>

// MHCLayerAITER: x[B,4,2048] fp32 -> out[B,4,2048] fp32
// out[b,i,c] = sum_j M[i,j]*x[b,j,c] + 2*sig(H_post[i]) * y_norm[b,c]
// y_norm[b,c] = bf16(sum_j sig(H_pre[j])*x[b,j,c]) / rms_b * bf16(w[c])
// M = sinkhorn3(exp(H_res))  (4x4)
//
// R3 = R2 resubmission (R2 bench was an infra failure, never measured).
// Barrier-free wave-per-b design:
//  - Each 64-lane wave owns one b: 32 c-values/lane, rms reduction is a
//    pure __shfl_xor wave reduce. NO __syncthreads, NO LDS anywhere ->
//    no compiler-emitted "s_waitcnt vmcnt(0) before s_barrier" drain that
//    serialized R1's register pipeline (4 full-latency stalls per block).
//  - Sinkhorn/sigmoid constants computed redundantly per-thread (~300
//    VALU cycles) WHILE the 32 nt x-loads are in flight, then
//    readfirstlane'd into SGPRs. Setup kernel + d_ws usage deleted.
//  - Load order: w raw (8 loads) first, then x (32 loads). In-order vmcnt
//    means waiting for x never waits on anything issued later.
//  - y_norm folded into a single yn[] array post-rms to cut peak VGPRs.

namespace {

constexpr int N = 4;
constexpr int C = 2048;
constexpr int BLOCK = 256;
constexpr int WPB = BLOCK / 64;   // 4 waves per block, one b per wave
constexpr int CPL = C / 64;       // 32 c-values per lane
constexpr int VEC = CPL / 4;      // 8 float4 chunks per stream per lane
constexpr float EPSF = 1e-6f;

typedef float f4 __attribute__((ext_vector_type(4)));

__device__ __forceinline__ float bf16r(float v) {
    return __bfloat162float(__float2bfloat16(v));
}
// wave-uniform value -> SGPR
__device__ __forceinline__ float rfl(float v) {
    return __uint_as_float(__builtin_amdgcn_readfirstlane(__float_as_uint(v)));
}

__global__ __launch_bounds__(BLOCK, 2) void mhc_kernel(
    const float* __restrict__ x,      // [B,N,C]
    const float* __restrict__ w,      // [C]
    const float* __restrict__ H_pre,  // [N]
    const float* __restrict__ H_post, // [N]
    const float* __restrict__ H_res,  // [N,N]
    float* __restrict__ out,          // [B,N,C]
    int B)
{
    const int lane = threadIdx.x & 63;
    const int wv   = threadIdx.x >> 6;
    const int b    = blockIdx.x * WPB + wv;
    if (b >= B) return;   // wave-uniform exit

    // ---- issue all global loads first (w raw, then x nt, coalesced) ----
    f4 wraw[VEC];
    #pragma unroll
    for (int v = 0; v < VEC; ++v)
        wraw[v] = *(const f4*)(w + (size_t)(v * 64 + lane) * 4);

    const size_t base = (size_t)b * (N * C);
    float xs[N][CPL];
    #pragma unroll
    for (int j = 0; j < N; ++j) {
        #pragma unroll
        for (int v = 0; v < VEC; ++v) {
            const f4 tmp = __builtin_nontemporal_load(
                (const f4*)(x + base + (size_t)j * C + (size_t)(v * 64 + lane) * 4));
            #pragma unroll
            for (int k = 0; k < 4; ++k) xs[j][v * 4 + k] = tmp[k];
        }
    }

    // ---- constants: computed per-thread while loads are in flight ----
    float pre[N], post[N], P[N][N];
    #pragma unroll
    for (int j = 0; j < N; ++j) {
        pre[j]  = 1.0f / (1.0f + expf(-H_pre[j]));
        post[j] = 2.0f / (1.0f + expf(-H_post[j]));
    }
    #pragma unroll
    for (int i = 0; i < N; ++i)
        #pragma unroll
        for (int j = 0; j < N; ++j)
            P[i][j] = expf(H_res[i * N + j]);
    #pragma unroll
    for (int it = 0; it < 3; ++it) {
        #pragma unroll
        for (int i = 0; i < N; ++i) {
            const float rs = P[i][0] + P[i][1] + P[i][2] + P[i][3] + EPSF;
            #pragma unroll
            for (int j = 0; j < N; ++j) P[i][j] /= rs;
        }
        #pragma unroll
        for (int j = 0; j < N; ++j) {
            const float cs = P[0][j] + P[1][j] + P[2][j] + P[3][j] + EPSF;
            #pragma unroll
            for (int i = 0; i < N; ++i) P[i][j] /= cs;
        }
    }
    // uniform values -> SGPRs (frees VGPRs; VALU ops take 1 SGPR operand)
    #pragma unroll
    for (int j = 0; j < N; ++j) { pre[j] = rfl(pre[j]); post[j] = rfl(post[j]); }
    #pragma unroll
    for (int i = 0; i < N; ++i)
        #pragma unroll
        for (int j = 0; j < N; ++j)
            P[i][j] = rfl(P[i][j]);

    // ---- sigmoid-weighted aggregate, bf16 round, sum of squares ----
    float agg[CPL];
    float ss = 0.0f;
    #pragma unroll
    for (int k = 0; k < CPL; ++k) {
        float a = pre[0] * xs[0][k] + pre[1] * xs[1][k]
                + pre[2] * xs[2][k] + pre[3] * xs[3][k];
        a = bf16r(a);
        agg[k] = a;
        ss += a * a;
    }

    // ---- rms: pure wave reduction (64 lanes x 32 vals = full C row) ----
    #pragma unroll
    for (int off = 32; off > 0; off >>= 1) ss += __shfl_xor(ss, off, 64);
    const float rinv = 1.0f / sqrtf(ss * (1.0f / (float)C) + EPSF);

    // yn = (agg * rinv) * bf16(w)  -- folded in place, frees wraw
    float yn[CPL];
    #pragma unroll
    for (int v = 0; v < VEC; ++v)
        #pragma unroll
        for (int k = 0; k < 4; ++k)
            yn[v * 4 + k] = agg[v * 4 + k] * rinv * bf16r(wraw[v][k]);

    // ---- mix streams + combine, write all 4 output rows (nt stores) ----
    #pragma unroll
    for (int i = 0; i < N; ++i) {
        #pragma unroll
        for (int v = 0; v < VEC; ++v) {
            f4 o;
            #pragma unroll
            for (int k4 = 0; k4 < 4; ++k4) {
                const int idx = v * 4 + k4;
                o[k4] = P[i][0] * xs[0][idx] + P[i][1] * xs[1][idx]
                      + P[i][2] * xs[2][idx] + P[i][3] * xs[3][idx]
                      + post[i] * yn[idx];
            }
            __builtin_nontemporal_store(
                o, (f4*)(out + base + (size_t)i * C + (size_t)(v * 64 + lane) * 4));
        }
    }
}

}  // namespace

extern "C" void kernel_launch(void* const* d_in, const int* in_sizes, int n_in,
                              void* d_out, int out_size, void* d_ws, size_t ws_size,
                              hipStream_t stream) {
    const float* x      = (const float*)d_in[0];
    const float* w      = (const float*)d_in[1];
    const float* H_pre  = (const float*)d_in[2];
    const float* H_post = (const float*)d_in[3];
    const float* H_res  = (const float*)d_in[4];
    float* out = (float*)d_out;
    (void)d_ws; (void)ws_size;   // workspace intentionally unused

    const int B = in_sizes[0] / (N * C);   // 8192

    const int grid = (B + WPB - 1) / WPB;  // 2048 blocks x 4 independent waves
    mhc_kernel<<<dim3(grid), dim3(BLOCK), 0, stream>>>(
        x, w, H_pre, H_post, H_res, out, B);
}